// Round 1
// baseline (414.469 us; speedup 1.0000x reference)
//
#include <hip/hip_runtime.h>
#include <math.h>

// Problem constants
#define BATCH   8
#define LSEQ    4096      // 64*64
#define CMODEL  128
#define DIN     256
#define NSTATE  16
#define RRANK   8
#define NCH     64        // chunks per sequence
#define TCH     64        // timesteps per chunk (NCH*TCH == LSEQ)

__device__ __forceinline__ float sigmoidf_(float x) { return 1.0f / (1.0f + __expf(-x)); }
__device__ __forceinline__ float siluf_(float x)    { return x * sigmoidf_(x); }
__device__ __forceinline__ float softplusf_(float x) {
    return fmaxf(x, 0.0f) + log1pf(__expf(-fabsf(x)));
}

// ---------------------------------------------------------------------------
// K1: xz = x @ W_in ; split into xh_raw (cols 0..255) and z_silu = silu(z)
// x[b,l,c] = x_hsi[b,c,l].  Tile 64(l) x 64(j), K=128 in 2 chunks of 64.
// grid (512, 8), block 256
// ---------------------------------------------------------------------------
__global__ __launch_bounds__(256) void k1_gemm_in(
    const float* __restrict__ x_hsi, const float* __restrict__ W_in,
    float* __restrict__ xh_raw, float* __restrict__ z_silu)
{
    __shared__ float xs[64][64];   // xs[k][l]
    __shared__ float ws[64][64];   // ws[k][j]
    const int tid = threadIdx.x;
    const int R0  = blockIdx.x * 64;          // global row (b*L + l)
    const int b   = R0 >> 12;
    const int l0  = R0 & 4095;
    const int j0  = blockIdx.y * 64;
    const int tx  = tid & 15, ty = tid >> 4;

    float acc[4][4];
    #pragma unroll
    for (int i = 0; i < 4; ++i)
        #pragma unroll
        for (int j = 0; j < 4; ++j) acc[i][j] = 0.0f;

    for (int kc = 0; kc < 128; kc += 64) {
        #pragma unroll
        for (int it = 0; it < 4; ++it) {
            int idx4 = tid + it * 256;            // 1024 float4 per tile
            int c = idx4 >> 4, i4 = idx4 & 15;
            float4 v = *(const float4*)&x_hsi[((b * 128 + kc + c) << 12) + l0 + i4 * 4];
            *(float4*)&xs[c][i4 * 4] = v;
            float4 w = *(const float4*)&W_in[(kc + c) * 512 + j0 + i4 * 4];
            *(float4*)&ws[c][i4 * 4] = w;
        }
        __syncthreads();
        #pragma unroll 8
        for (int k = 0; k < 64; ++k) {
            float4 a  = *(const float4*)&xs[k][ty * 4];
            float4 bb = *(const float4*)&ws[k][tx * 4];
            float av[4] = {a.x, a.y, a.z, a.w};
            float bv[4] = {bb.x, bb.y, bb.z, bb.w};
            #pragma unroll
            for (int i = 0; i < 4; ++i)
                #pragma unroll
                for (int j = 0; j < 4; ++j) acc[i][j] = fmaf(av[i], bv[j], acc[i][j]);
        }
        __syncthreads();
    }

    const bool is_xh = (j0 < 256);
    #pragma unroll
    for (int i = 0; i < 4; ++i) {
        int gr = R0 + ty * 4 + i;
        float4 v = make_float4(acc[i][0], acc[i][1], acc[i][2], acc[i][3]);
        if (is_xh) {
            *(float4*)&xh_raw[gr * 256 + j0 + tx * 4] = v;
        } else {
            v.x = siluf_(v.x); v.y = siluf_(v.y); v.z = siluf_(v.z); v.w = siluf_(v.w);
            *(float4*)&z_silu[gr * 256 + (j0 - 256) + tx * 4] = v;
        }
    }
}

// ---------------------------------------------------------------------------
// K4: xdbl[row, 0:40] = conv_silu(xh_raw)[row,:] @ W_x   (conv inlined)
// thread = one row (b*L+l); W_x + conv params staged in LDS.
// grid 128, block 256
// ---------------------------------------------------------------------------
__global__ __launch_bounds__(256) void k4_xdbl(
    const float* __restrict__ xh_raw, const float* __restrict__ conv_w,
    const float* __restrict__ conv_b, const float* __restrict__ W_x,
    float* __restrict__ xdbl)
{
    __shared__ float wl[256 * 40];
    __shared__ float cw0[256], cw1[256], cbs[256];
    const int tid = threadIdx.x;
    #pragma unroll
    for (int it = 0; it < 10; ++it) {
        int i4 = tid + it * 256;                  // 2560 float4 = 10240 floats
        ((float4*)wl)[i4] = ((const float4*)W_x)[i4];
    }
    cw0[tid] = conv_w[2 * tid];
    cw1[tid] = conv_w[2 * tid + 1];
    cbs[tid] = conv_b[tid];
    __syncthreads();

    const int row = blockIdx.x * 256 + tid;
    const int l   = row & 4095;
    const bool has_prev = (l > 0);
    const float4* xr = (const float4*)&xh_raw[row * 256];
    const float4* xp = (const float4*)&xh_raw[(row - 1) * 256];

    float4 acc[10];
    #pragma unroll
    for (int m = 0; m < 10; ++m) acc[m] = make_float4(0.f, 0.f, 0.f, 0.f);

    for (int k4 = 0; k4 < 64; ++k4) {
        float4 cur = xr[k4];
        float4 prv = has_prev ? xp[k4] : make_float4(0.f, 0.f, 0.f, 0.f);
        float cu[4] = {cur.x, cur.y, cur.z, cur.w};
        float pv[4] = {prv.x, prv.y, prv.z, prv.w};
        #pragma unroll
        for (int kk = 0; kk < 4; ++kk) {
            int d = k4 * 4 + kk;
            float pre = pv[kk] * cw0[d] + cu[kk] * cw1[d] + cbs[d];
            float v = siluf_(pre);
            const float4* wr = (const float4*)&wl[d * 40];
            #pragma unroll
            for (int m = 0; m < 10; ++m) {
                float4 w = wr[m];
                acc[m].x = fmaf(v, w.x, acc[m].x);
                acc[m].y = fmaf(v, w.y, acc[m].y);
                acc[m].z = fmaf(v, w.z, acc[m].z);
                acc[m].w = fmaf(v, w.w, acc[m].w);
            }
        }
    }
    float4* outr = (float4*)&xdbl[row * 40];
    #pragma unroll
    for (int m = 0; m < 10; ++m) outr[m] = acc[m];
}

// ---------------------------------------------------------------------------
// Scan pass 1: per (b, chunk, d): local h (h_in=0) and decay product P.
// conv+silu and dt=softplus(dtlow@W_dt+b_dt) computed inline.
// grid (NCH, BATCH), block 256 (thread = d)
// ---------------------------------------------------------------------------
__global__ __launch_bounds__(256) void k6_scan1(
    const float* __restrict__ xh_raw, const float* __restrict__ xdbl,
    const float* __restrict__ conv_w, const float* __restrict__ conv_b,
    const float* __restrict__ W_dt, const float* __restrict__ b_dt,
    const float* __restrict__ A_log,
    float* __restrict__ hend, float* __restrict__ Pprod)
{
    const int d = threadIdx.x;
    const int chunk = blockIdx.x;
    const int b = blockIdx.y;

    float A[16];
    #pragma unroll
    for (int q = 0; q < 4; ++q) {
        float4 al = *(const float4*)&A_log[d * 16 + q * 4];
        A[q*4+0] = -expf(al.x); A[q*4+1] = -expf(al.y);
        A[q*4+2] = -expf(al.z); A[q*4+3] = -expf(al.w);
    }
    float wdt[8];
    #pragma unroll
    for (int r = 0; r < 8; ++r) wdt[r] = W_dt[r * 256 + d];
    const float bdt = b_dt[d];
    const float w0 = conv_w[2 * d], w1 = conv_w[2 * d + 1], cb = conv_b[d];

    float h[16], P[16];
    #pragma unroll
    for (int n = 0; n < 16; ++n) { h[n] = 0.f; P[n] = 1.f; }

    const int t0 = b * LSEQ + chunk * TCH;       // global row
    float prev = (chunk > 0) ? xh_raw[(t0 - 1) * 256 + d] : 0.f;

    for (int tt = 0; tt < TCH; ++tt) {
        const int row = t0 + tt;
        float cur = xh_raw[row * 256 + d];
        float xcv = siluf_(prev * w0 + cur * w1 + cb);
        prev = cur;

        const float4* bc4 = (const float4*)&xdbl[row * 40];
        float dl[8];
        *(float4*)&dl[0] = bc4[0]; *(float4*)&dl[4] = bc4[1];
        float dtr = bdt;
        #pragma unroll
        for (int r = 0; r < 8; ++r) dtr = fmaf(dl[r], wdt[r], dtr);
        float dtv = softplusf_(dtr);

        float Bt[16];
        *(float4*)&Bt[0]  = bc4[2]; *(float4*)&Bt[4]  = bc4[3];
        *(float4*)&Bt[8]  = bc4[4]; *(float4*)&Bt[12] = bc4[5];

        float dtx = dtv * xcv;
        #pragma unroll
        for (int n = 0; n < 16; ++n) {
            float dA = __expf(dtv * A[n]);
            h[n] = fmaf(dA, h[n], dtx * Bt[n]);
            P[n] *= dA;
        }
    }

    const int base = ((b * NCH + chunk) * 256 + d) * 16;
    #pragma unroll
    for (int q = 0; q < 4; ++q) {
        *(float4*)&hend[base + q * 4]  = make_float4(h[q*4], h[q*4+1], h[q*4+2], h[q*4+3]);
        *(float4*)&Pprod[base + q * 4] = make_float4(P[q*4], P[q*4+1], P[q*4+2], P[q*4+3]);
    }
}

// ---------------------------------------------------------------------------
// Scan pass 2: sequential combine over chunks; thread = (b, d, n).
// grid 128, block 256
// ---------------------------------------------------------------------------
__global__ __launch_bounds__(256) void k7_combine(
    const float* __restrict__ hend, const float* __restrict__ Pprod,
    float* __restrict__ hin)
{
    const int idx = blockIdx.x * 256 + threadIdx.x;   // b*4096 + d*16 + n
    const int b = idx >> 12;
    const int rem = idx & 4095;
    float h = 0.f;
    for (int c = 0; c < NCH; ++c) {
        const int o = ((b * NCH + c) << 12) + rem;
        hin[o] = h;
        h = fmaf(Pprod[o], h, hend[o]);
    }
}

// ---------------------------------------------------------------------------
// Scan pass 3: replay with correct h_in, emit y = (scan + xc*D) * z_silu
// grid (NCH, BATCH), block 256
// ---------------------------------------------------------------------------
__global__ __launch_bounds__(256) void k8_scan2(
    const float* __restrict__ xh_raw, const float* __restrict__ xdbl,
    const float* __restrict__ conv_w, const float* __restrict__ conv_b,
    const float* __restrict__ W_dt, const float* __restrict__ b_dt,
    const float* __restrict__ A_log, const float* __restrict__ Dvec,
    const float* __restrict__ z_silu, const float* __restrict__ hin,
    float* __restrict__ ybuf)
{
    const int d = threadIdx.x;
    const int chunk = blockIdx.x;
    const int b = blockIdx.y;

    float A[16];
    #pragma unroll
    for (int q = 0; q < 4; ++q) {
        float4 al = *(const float4*)&A_log[d * 16 + q * 4];
        A[q*4+0] = -expf(al.x); A[q*4+1] = -expf(al.y);
        A[q*4+2] = -expf(al.z); A[q*4+3] = -expf(al.w);
    }
    float wdt[8];
    #pragma unroll
    for (int r = 0; r < 8; ++r) wdt[r] = W_dt[r * 256 + d];
    const float bdt = b_dt[d];
    const float w0 = conv_w[2 * d], w1 = conv_w[2 * d + 1], cb = conv_b[d];
    const float Dd = Dvec[d];

    float h[16];
    const int hbase = ((b * NCH + chunk) * 256 + d) * 16;
    #pragma unroll
    for (int q = 0; q < 4; ++q) {
        float4 hv = *(const float4*)&hin[hbase + q * 4];
        h[q*4+0] = hv.x; h[q*4+1] = hv.y; h[q*4+2] = hv.z; h[q*4+3] = hv.w;
    }

    const int t0 = b * LSEQ + chunk * TCH;
    float prev = (chunk > 0) ? xh_raw[(t0 - 1) * 256 + d] : 0.f;

    for (int tt = 0; tt < TCH; ++tt) {
        const int row = t0 + tt;
        float cur = xh_raw[row * 256 + d];
        float xcv = siluf_(prev * w0 + cur * w1 + cb);
        prev = cur;

        const float4* bc4 = (const float4*)&xdbl[row * 40];
        float dl[8];
        *(float4*)&dl[0] = bc4[0]; *(float4*)&dl[4] = bc4[1];
        float dtr = bdt;
        #pragma unroll
        for (int r = 0; r < 8; ++r) dtr = fmaf(dl[r], wdt[r], dtr);
        float dtv = softplusf_(dtr);

        float Bt[16], Ct[16];
        *(float4*)&Bt[0]  = bc4[2]; *(float4*)&Bt[4]  = bc4[3];
        *(float4*)&Bt[8]  = bc4[4]; *(float4*)&Bt[12] = bc4[5];
        *(float4*)&Ct[0]  = bc4[6]; *(float4*)&Ct[4]  = bc4[7];
        *(float4*)&Ct[8]  = bc4[8]; *(float4*)&Ct[12] = bc4[9];

        float dtx = dtv * xcv;
        float yv = 0.f;
        #pragma unroll
        for (int n = 0; n < 16; ++n) {
            float dA = __expf(dtv * A[n]);
            h[n] = fmaf(dA, h[n], dtx * Bt[n]);
            yv = fmaf(h[n], Ct[n], yv);
        }
        yv = fmaf(Dd, xcv, yv);
        float zs = z_silu[row * 256 + d];
        ybuf[row * 256 + d] = yv * zs;
    }
}

// ---------------------------------------------------------------------------
// K9: out_mm[b,c,l] = sum_k y[b,l,k] * W_out[k,c]   (stores transposed)
// Tile 64(l) x 64(c), K=256 in 4 chunks. grid (512, 2), block 256
// ---------------------------------------------------------------------------
__global__ __launch_bounds__(256) void k9_gemm_out(
    const float* __restrict__ ybuf, const float* __restrict__ W_out,
    float* __restrict__ out_mm)
{
    __shared__ float ys[64][68];   // ys[k][l]  (+4 pad: aligned float4, spread banks)
    __shared__ float wt[64][68];   // wt[k][c]
    const int tid = threadIdx.x;
    const int R0 = blockIdx.x * 64;
    const int b  = R0 >> 12;
    const int l0 = R0 & 4095;
    const int c0 = blockIdx.y * 64;
    const int tx = tid & 15, ty = tid >> 4;   // tx: l dim, ty: c dim

    float acc[4][4];  // [c][l]
    #pragma unroll
    for (int i = 0; i < 4; ++i)
        #pragma unroll
        for (int j = 0; j < 4; ++j) acc[i][j] = 0.0f;

    for (int kc = 0; kc < 256; kc += 64) {
        #pragma unroll
        for (int it = 0; it < 4; ++it) {
            int idx4 = tid + it * 256;
            int r = idx4 >> 4, q4 = idx4 & 15;
            float4 v = *(const float4*)&ybuf[(R0 + r) * 256 + kc + q4 * 4];
            ys[q4*4+0][r] = v.x; ys[q4*4+1][r] = v.y;
            ys[q4*4+2][r] = v.z; ys[q4*4+3][r] = v.w;
            float4 w = *(const float4*)&W_out[(kc + r) * 128 + c0 + q4 * 4];
            *(float4*)&wt[r][q4 * 4] = w;
        }
        __syncthreads();
        #pragma unroll 8
        for (int k = 0; k < 64; ++k) {
            float4 a  = *(const float4*)&ys[k][tx * 4];
            float4 bb = *(const float4*)&wt[k][ty * 4];
            float av[4] = {a.x, a.y, a.z, a.w};
            float bv[4] = {bb.x, bb.y, bb.z, bb.w};
            #pragma unroll
            for (int i = 0; i < 4; ++i)
                #pragma unroll
                for (int j = 0; j < 4; ++j) acc[i][j] = fmaf(bv[i], av[j], acc[i][j]);
        }
        __syncthreads();
    }
    #pragma unroll
    for (int i = 0; i < 4; ++i) {
        int c = c0 + ty * 4 + i;
        float4 v = make_float4(acc[i][0], acc[i][1], acc[i][2], acc[i][3]);
        *(float4*)&out_mm[(b * 128 + c) * 4096 + l0 + tx * 4] = v;
    }
}

// ---------------------------------------------------------------------------
// K10a: partial sums for GroupNorm. block = (b,g,slice of 16384 floats)
// grid 256, block 256
// ---------------------------------------------------------------------------
__global__ __launch_bounds__(256) void k10a_gnpart(
    const float* __restrict__ out_mm, float* __restrict__ part)
{
    const int bid = blockIdx.x;
    const int b = bid >> 5, g = (bid >> 3) & 3, s = bid & 7;
    const float* base = out_mm + (b * 128 + g * 32) * 4096 + s * 16384;
    const int tid = threadIdx.x;
    float sum = 0.f, ssq = 0.f;
    #pragma unroll 4
    for (int it = 0; it < 16; ++it) {
        float4 v = *(const float4*)&base[(tid + it * 256) * 4];
        sum += v.x + v.y + v.z + v.w;
        ssq += v.x*v.x + v.y*v.y + v.z*v.z + v.w*v.w;
    }
    #pragma unroll
    for (int off = 32; off > 0; off >>= 1) {
        sum += __shfl_down(sum, off, 64);
        ssq += __shfl_down(ssq, off, 64);
    }
    __shared__ float ls[8];
    const int wid = tid >> 6, lane = tid & 63;
    if (lane == 0) { ls[wid * 2] = sum; ls[wid * 2 + 1] = ssq; }
    __syncthreads();
    if (tid == 0) {
        float S = ls[0] + ls[2] + ls[4] + ls[6];
        float Q = ls[1] + ls[3] + ls[5] + ls[7];
        part[bid * 2]     = S;
        part[bid * 2 + 1] = Q;
    }
}

// K10b: finalize mean / rsqrt(var+eps) per (b,g). grid 1, block 64
__global__ void k10b_gnstat(const float* __restrict__ part, float* __restrict__ stat)
{
    const int tid = threadIdx.x;
    if (tid < 32) {
        float S = 0.f, Q = 0.f;
        for (int s = 0; s < 8; ++s) {
            S += part[(tid * 8 + s) * 2];
            Q += part[(tid * 8 + s) * 2 + 1];
        }
        const float inv_n = 1.0f / 131072.0f;
        float mean = S * inv_n;
        float var  = Q * inv_n - mean * mean;
        stat[tid * 2]     = mean;
        stat[tid * 2 + 1] = rsqrtf(var + 1e-5f);
    }
}

// K10c: apply GN + silu + residual. grid 4096, block 256
__global__ __launch_bounds__(256) void k10c_apply(
    const float* __restrict__ out_mm, const float* __restrict__ stat,
    const float* __restrict__ gamma, const float* __restrict__ beta,
    const float* __restrict__ x_hsi, float* __restrict__ out)
{
    const int idx4 = blockIdx.x * 256 + threadIdx.x;
    const int flat = idx4 * 4;
    const int c = (flat >> 12) & 127;
    const int b = flat >> 19;
    const int g = c >> 5;
    const float mean = stat[(b * 4 + g) * 2];
    const float inv  = stat[(b * 4 + g) * 2 + 1];
    const float ga = gamma[c], be = beta[c];
    float4 v = *(const float4*)&out_mm[flat];
    float4 r = *(const float4*)&x_hsi[flat];
    float o[4];
    float vv[4] = {v.x, v.y, v.z, v.w};
    float rr[4] = {r.x, r.y, r.z, r.w};
    #pragma unroll
    for (int q = 0; q < 4; ++q) {
        float xn = (vv[q] - mean) * inv;
        float gv = xn * ga + be;
        o[q] = siluf_(gv) + rr[q];
    }
    *(float4*)&out[flat] = make_float4(o[0], o[1], o[2], o[3]);
}

// ---------------------------------------------------------------------------
extern "C" void kernel_launch(void* const* d_in, const int* in_sizes, int n_in,
                              void* d_out, int out_size, void* d_ws, size_t ws_size,
                              hipStream_t stream)
{
    const float* x_hsi  = (const float*)d_in[0];
    const float* W_in   = (const float*)d_in[1];
    const float* conv_w = (const float*)d_in[2];
    const float* conv_b = (const float*)d_in[3];
    const float* W_x    = (const float*)d_in[4];
    const float* W_dt   = (const float*)d_in[5];
    const float* b_dt   = (const float*)d_in[6];
    const float* A_log  = (const float*)d_in[7];
    const float* Dv     = (const float*)d_in[8];
    const float* W_out  = (const float*)d_in[9];
    const float* gnw    = (const float*)d_in[10];
    const float* gnb    = (const float*)d_in[11];

    float* ws = (float*)d_ws;
    float* xh_raw = ws + 0;           // 8,388,608
    float* z_silu = ws + 8388608;     // 8,388,608
    float* ybuf   = ws + 16777216;    // 8,388,608
    float* out_mm = ws + 25165824;    // 4,194,304
    float* xdbl   = ws + 29360128;    // 1,310,720  (dtlow 8 | B 16 | C 16)
    float* hend   = ws + 30670848;    // 2,097,152
    float* Pp     = ws + 32768000;    // 2,097,152
    float* hin    = ws + 34865152;    // 2,097,152
    float* part   = ws + 36962304;    // 512
    float* stat   = ws + 36962816;    // 64
    float* outp   = (float*)d_out;

    k1_gemm_in<<<dim3(512, 8), 256, 0, stream>>>(x_hsi, W_in, xh_raw, z_silu);
    k4_xdbl<<<128, 256, 0, stream>>>(xh_raw, conv_w, conv_b, W_x, xdbl);
    k6_scan1<<<dim3(NCH, BATCH), 256, 0, stream>>>(xh_raw, xdbl, conv_w, conv_b,
                                                   W_dt, b_dt, A_log, hend, Pp);
    k7_combine<<<128, 256, 0, stream>>>(hend, Pp, hin);
    k8_scan2<<<dim3(NCH, BATCH), 256, 0, stream>>>(xh_raw, xdbl, conv_w, conv_b,
                                                   W_dt, b_dt, A_log, Dv, z_silu, hin, ybuf);
    k9_gemm_out<<<dim3(512, 2), 256, 0, stream>>>(ybuf, W_out, out_mm);
    k10a_gnpart<<<256, 256, 0, stream>>>(out_mm, part);
    k10b_gnstat<<<1, 64, 0, stream>>>(part, stat);
    k10c_apply<<<4096, 256, 0, stream>>>(out_mm, stat, gnw, gnb, x_hsi, outp);
}